// Round 11
// baseline (421.086 us; speedup 1.0000x reference)
//
#include <hip/hip_runtime.h>

#define B_  2
#define L_  2048
#define H_  8
#define E_  64
#define U_  40
#define LK_ 2048

#define KA_BLOCKS 8192  // B_*H_*L_/4 waves of kA work, 4 waves/block

typedef float floatv4 __attribute__((ext_vector_type(4)));

// ---------------------------------------------------------------------------
// kAVm: fused kA + kVm (saves one launch gap).
// Blocks [0,8192): M[b,h,l] = max_s(Q.K_sample) - sum_s/L_K, one wave per l.
// Blocks [8192,8320): V column partial sums (16 bh x 8 chunks).
// ---------------------------------------------------------------------------
__global__ __launch_bounds__(256) void kAVm(
    const float* __restrict__ Q, const float* __restrict__ K,
    const float* __restrict__ V, const int* __restrict__ idxs,
    float* __restrict__ M, float* __restrict__ partialV, int S) {
  if (blockIdx.x < KA_BLOCKS) {
    // ---- kA role: wave in [0, 32768) covers all (b,h,l) ----
    int wave = blockIdx.x * 4 + (threadIdx.x >> 6);
    int lane = threadIdx.x & 63;
    int l = wave & (L_ - 1);
    int h = (wave >> 11) & (H_ - 1);
    int b = wave >> 14;
    int g = lane >> 4;    // sample slot 0..3
    int e4 = lane & 15;   // float4 slot within row
    const float4* Q4 = (const float4*)Q;
    const float4* K4 = (const float4*)K;
    int qrow = ((b * L_ + l) * H_ + h) << 4;
    float4 qv = Q4[qrow + e4];
    int myidx = (lane < S) ? idxs[(size_t)l * S + lane] : 0;
    float vmax = -3.0e38f, vsum = 0.0f;
    int nb = (S + 3) >> 2;
#pragma unroll 2
    for (int t = 0; t < nb; ++t) {
      int s = 4 * t + g;
      int kidx = __shfl(myidx, (s < S) ? s : 0, 64);
      int krow = ((b * L_ + kidx) * H_ + h) << 4;
      float4 kv = K4[krow + e4];
      float p = qv.x * kv.x + qv.y * kv.y + qv.z * kv.z + qv.w * kv.w;
      p += __shfl_xor(p, 1, 64);
      p += __shfl_xor(p, 2, 64);
      p += __shfl_xor(p, 4, 64);
      p += __shfl_xor(p, 8, 64);
      if (s < S) { vmax = fmaxf(vmax, p); vsum += p; }
    }
    vmax = fmaxf(vmax, __shfl_xor(vmax, 16, 64));
    vmax = fmaxf(vmax, __shfl_xor(vmax, 32, 64));
    vsum += __shfl_xor(vsum, 16, 64);
    vsum += __shfl_xor(vsum, 32, 64);
    if (lane == 0) M[(b * H_ + h) * L_ + l] = vmax - vsum * (1.0f / (float)LK_);
  } else {
    // ---- kVm role ----
    int blk = blockIdx.x - KA_BLOCKS;
    int bh = blk >> 3, c = blk & 7;
    int b = bh >> 3, h = bh & 7;
    int t = threadIdx.x, lane = t & 63, w = t >> 6;
    int l0 = c * 256 + w * 64;
    float acc = 0.0f;
#pragma unroll 4
    for (int i = 0; i < 64; ++i)
      acc += V[(((b * L_ + l0 + i) * H_ + h) << 6) + lane];
    __shared__ float cred[4][64];
    cred[w][lane] = acc;
    __syncthreads();
    if (w == 0)
      partialV[(bh * 8 + c) * 64 + lane] =
          cred[0][lane] + cred[1][lane] + cred[2][lane] + cred[3][lane];
  }
}

// ---------------------------------------------------------------------------
// kB2: per (b,h): stable top-40 of M row, ONE WAVE, registers + static
// indexing only. Tie-break: lowest index. Also finishes V-mean.
// ---------------------------------------------------------------------------
__global__ __launch_bounds__(64) void kB2_topk(
    const float* __restrict__ M, const float* __restrict__ partialV,
    int* __restrict__ Mtop, float* __restrict__ meanV) {
  int bh = blockIdx.x;
  int lane = threadIdx.x;
  float v[32];
  int base = bh * L_;
#pragma unroll
  for (int i = 0; i < 32; ++i) v[i] = M[base + lane + i * 64];
  for (int it = 0; it < U_; ++it) {
    float best = -3.0e38f;
    int bi = 0x7fffffff;
#pragma unroll
    for (int i = 0; i < 32; ++i) {
      if (v[i] > best) { best = v[i]; bi = lane + i * 64; }
    }
#pragma unroll
    for (int off = 32; off > 0; off >>= 1) {
      float ov = __shfl_xor(best, off, 64);
      int oi = __shfl_xor(bi, off, 64);
      if (ov > best || (ov == best && oi < bi)) { best = ov; bi = oi; }
    }
    if (lane == 0) Mtop[bh * U_ + it] = bi;
    if ((bi & 63) == lane) {
#pragma unroll
      for (int i = 0; i < 32; ++i)
        if ((bi >> 6) == i) v[i] = -3.0e38f;
    }
  }
  float s = 0.0f;
#pragma unroll
  for (int c = 0; c < 8; ++c) s += partialV[(bh * 8 + c) * 64 + lane];
  meanV[(bh << 6) + lane] = s * (1.0f / (float)L_);
}

// ---------------------------------------------------------------------------
// kC: the big fill, branch-free: loop1 broadcasts meanV into out0, loop2
// streams 1/LK into out1 via non-temporal ext_vector stores (never re-read).
// ---------------------------------------------------------------------------
__global__ __launch_bounds__(256) void kC_fill(
    floatv4* __restrict__ out0, floatv4* __restrict__ out1,
    const float* __restrict__ meanV) {
  const int N0 = (B_ * L_ * H_ * E_) / 4;    // 524288
  const int N1 = (B_ * H_ * LK_ * LK_) / 4;  // 16777216
  const float iv = 1.0f / (float)LK_;
  const floatv4 fv = {iv, iv, iv, iv};
  int stride = gridDim.x * blockDim.x;
  int tid = blockIdx.x * blockDim.x + threadIdx.x;
  for (int i = tid; i < N0; i += stride) {
    int e4 = i & 15;
    int h = (i >> 4) & 7;
    int b = i >> 18;
    const floatv4* mp = (const floatv4*)(meanV + ((((b << 3) + h)) << 6));
    __builtin_nontemporal_store(mp[e4], &out0[i]);
  }
  for (int i = tid; i < N1; i += stride) {
    __builtin_nontemporal_store(fv, &out1[i]);
  }
}

// ---------------------------------------------------------------------------
// kD: scores for the 40 selected queries, in place into attns rows (x 1/8).
// Grid = (b,h) x 32 key-chunks of 64. 65-pad keeps LDS conflict-free.
// ---------------------------------------------------------------------------
__global__ __launch_bounds__(256) void kD_scores(
    const float* __restrict__ Q, const float* __restrict__ K,
    const int* __restrict__ Mtop, float* __restrict__ out1) {
  int bh = blockIdx.x >> 5;
  int kc = blockIdx.x & 31;
  int b = bh >> 3, h = bh & 7;
  __shared__ float Kt[64][65];
  __shared__ float Qt[U_][65];
  __shared__ int rows[U_];
  int t = threadIdx.x;
  int k0 = kc << 6;
  for (int i = t; i < 64 * 64; i += 256) {
    int r = i >> 6, e = i & 63;
    Kt[r][e] = K[(((b * L_ + k0 + r) * H_ + h) << 6) + e];
  }
  if (t < U_) rows[t] = Mtop[bh * U_ + t];
  __syncthreads();
  for (int i = t; i < U_ * 64; i += 256) {
    int u = i >> 6, e = i & 63;
    Qt[u][e] = Q[(((b * L_ + rows[u]) * H_ + h) << 6) + e];
  }
  __syncthreads();
  for (int p = t; p < U_ * 64; p += 256) {
    int u = p >> 6, k = p & 63;
    float s = 0.0f;
#pragma unroll
    for (int e = 0; e < 64; ++e) s += Qt[u][e] * Kt[k][e];
    out1[(size_t)(bh * LK_ + rows[u]) * LK_ + (k0 + k)] = s * 0.125f;
  }
}

// ---------------------------------------------------------------------------
// kE: per selected row (640 wgs): in-place softmax, then ctx = p.V with
// float4 lanes (16 lanes/row, 4 rows in flight per wave).
// ---------------------------------------------------------------------------
__global__ __launch_bounds__(256) void kE_softmax_ctx(
    const float* __restrict__ V, const int* __restrict__ Mtop,
    float* __restrict__ out0, float* __restrict__ out1) {
  int gblk = blockIdx.x;
  int u = gblk % U_;
  int bh = gblk / U_;
  int b = bh >> 3, h = bh & 7;
  int t = threadIdx.x, lane = t & 63, w = t >> 6;
  int lu = Mtop[bh * U_ + u];
  float* row = out1 + (size_t)(bh * LK_ + lu) * LK_;
  float4* row4 = (float4*)row;
  float4 v0 = row4[t], v1 = row4[t + 256];
  float lmax = fmaxf(fmaxf(fmaxf(v0.x, v0.y), fmaxf(v0.z, v0.w)),
                     fmaxf(fmaxf(v1.x, v1.y), fmaxf(v1.z, v1.w)));
#pragma unroll
  for (int off = 32; off > 0; off >>= 1) lmax = fmaxf(lmax, __shfl_xor(lmax, off, 64));
  __shared__ float sred[4];
  if (lane == 0) sred[w] = lmax;
  __syncthreads();
  float gmax = fmaxf(fmaxf(sred[0], sred[1]), fmaxf(sred[2], sred[3]));
  __syncthreads();
  v0.x = __expf(v0.x - gmax); v0.y = __expf(v0.y - gmax);
  v0.z = __expf(v0.z - gmax); v0.w = __expf(v0.w - gmax);
  v1.x = __expf(v1.x - gmax); v1.y = __expf(v1.y - gmax);
  v1.z = __expf(v1.z - gmax); v1.w = __expf(v1.w - gmax);
  float lsum = v0.x + v0.y + v0.z + v0.w + v1.x + v1.y + v1.z + v1.w;
#pragma unroll
  for (int off = 32; off > 0; off >>= 1) lsum += __shfl_xor(lsum, off, 64);
  if (lane == 0) sred[w] = lsum;
  __syncthreads();
  float gsum = sred[0] + sred[1] + sred[2] + sred[3];
  float inv = 1.0f / gsum;
  v0.x *= inv; v0.y *= inv; v0.z *= inv; v0.w *= inv;
  v1.x *= inv; v1.y *= inv; v1.z *= inv; v1.w *= inv;
  __shared__ __attribute__((aligned(16))) float ps[2048];
  float4* ps4 = (float4*)ps;
  ps4[t] = v0; ps4[t + 256] = v1;
  row4[t] = v0; row4[t + 256] = v1;
  __syncthreads();
  // PV: wave w handles k in [w*512, w*512+512); 16 lanes per row, 4 rows/iter
  int g = lane >> 4, e4 = lane & 15;
  const float4* V4 = (const float4*)V;
  float4 acc = make_float4(0.f, 0.f, 0.f, 0.f);
  int kbase = w << 9;
#pragma unroll 4
  for (int kk = 0; kk < 512; kk += 4) {
    int k = kbase + kk + g;
    float pk = ps[k];
    int vrow = ((b * L_ + k) * H_ + h) << 4;
    float4 vv = V4[vrow + e4];
    acc.x += pk * vv.x; acc.y += pk * vv.y;
    acc.z += pk * vv.z; acc.w += pk * vv.w;
  }
#pragma unroll
  for (int off = 16; off <= 32; off <<= 1) {
    acc.x += __shfl_xor(acc.x, off, 64);
    acc.y += __shfl_xor(acc.y, off, 64);
    acc.z += __shfl_xor(acc.z, off, 64);
    acc.w += __shfl_xor(acc.w, off, 64);
  }
  __shared__ __attribute__((aligned(16))) float credf[4][64];
  if (lane < 16) *(float4*)&credf[w][e4 * 4] = acc;
  __syncthreads();
  if (w == 0) {
    float c = credf[0][lane] + credf[1][lane] + credf[2][lane] + credf[3][lane];
    out0[(((b * L_ + lu) * H_ + h) << 6) + lane] = c;
  }
}

// ---------------------------------------------------------------------------
extern "C" void kernel_launch(void* const* d_in, const int* in_sizes, int n_in,
                              void* d_out, int out_size, void* d_ws, size_t ws_size,
                              hipStream_t stream) {
  const float* Q = (const float*)d_in[0];
  const float* K = (const float*)d_in[1];
  const float* V = (const float*)d_in[2];
  const int* idxs = (const int*)d_in[3];
  int S = in_sizes[3] / L_;  // sample_k = 40

  float* out0 = (float*)d_out;
  float* out1 = out0 + (size_t)B_ * L_ * H_ * E_;

  // ws layout (floats): M[32768] | Mtop[640 i] | meanV[1024] | partialV[8192]
  float* M = (float*)d_ws;
  int* Mtop = (int*)((char*)d_ws + (size_t)32768 * 4);
  float* meanV = (float*)((char*)d_ws + (size_t)(32768 + 640) * 4);
  float* partialV = (float*)((char*)d_ws + (size_t)(32768 + 640 + 1024) * 4);

  kAVm<<<dim3(KA_BLOCKS + B_ * H_ * 8), dim3(256), 0, stream>>>(Q, K, V, idxs, M, partialV, S);
  kB2_topk<<<dim3(B_ * H_), dim3(64), 0, stream>>>(M, partialV, Mtop, meanV);
  kC_fill<<<dim3(4096), dim3(256), 0, stream>>>((floatv4*)out0, (floatv4*)out1, meanV);
  kD_scores<<<dim3(B_ * H_ * 32), dim3(256), 0, stream>>>(Q, K, Mtop, out1);
  kE_softmax_ctx<<<dim3(B_ * H_ * U_), dim3(256), 0, stream>>>(V, Mtop, out0, out1);
}

// Round 12
// 400.956 us; speedup vs baseline: 1.0502x; 1.0502x over previous
//
#include <hip/hip_runtime.h>

#define B_  2
#define L_  2048
#define H_  8
#define E_  64
#define U_  40
#define LK_ 2048

typedef float floatv4 __attribute__((ext_vector_type(4)));

// ---------------------------------------------------------------------------
// kAF: interleaved {kA, kA, fill} groups + kVm tail.
// Blocks [0,12288): grp=bx/3, r=bx%3. r<2 -> kA wave-block (8192 total),
//   r==2 -> out1-fill block (4096 total, 64KB each, nt-stores).
// Blocks [12288,12416): V column partial sums (16 bh x 8 chunks).
// Rationale: kA is L2/latency-bound, the 268MB fill is HBM-store-bound;
// co-resident blocks overlap the two resource profiles.
// ---------------------------------------------------------------------------
__global__ __launch_bounds__(256) void kAF(
    const float* __restrict__ Q, const float* __restrict__ K,
    const float* __restrict__ V, const int* __restrict__ idxs,
    float* __restrict__ M, float* __restrict__ partialV,
    floatv4* __restrict__ out1v, int S) {
  int bx = blockIdx.x;
  if (bx < 12288) {
    int grp = bx / 3, r = bx - grp * 3;
    if (r < 2) {
      // ---- kA role: wave-block index in [0,8192), 4 waves each ----
      int wave = (grp * 2 + r) * 4 + (threadIdx.x >> 6);
      int lane = threadIdx.x & 63;
      int l = wave & (L_ - 1);
      int h = (wave >> 11) & (H_ - 1);
      int b = wave >> 14;
      int g = lane >> 4;    // sample slot 0..3
      int e4 = lane & 15;   // float4 slot within row
      const float4* Q4 = (const float4*)Q;
      const float4* K4 = (const float4*)K;
      int qrow = ((b * L_ + l) * H_ + h) << 4;
      float4 qv = Q4[qrow + e4];
      int myidx = (lane < S) ? idxs[(size_t)l * S + lane] : 0;
      float vmax = -3.0e38f, vsum = 0.0f;
      int nb = (S + 3) >> 2;
#pragma unroll 2
      for (int t = 0; t < nb; ++t) {
        int s = 4 * t + g;
        int kidx = __shfl(myidx, (s < S) ? s : 0, 64);
        int krow = ((b * L_ + kidx) * H_ + h) << 4;
        float4 kv = K4[krow + e4];
        float p = qv.x * kv.x + qv.y * kv.y + qv.z * kv.z + qv.w * kv.w;
        p += __shfl_xor(p, 1, 64);
        p += __shfl_xor(p, 2, 64);
        p += __shfl_xor(p, 4, 64);
        p += __shfl_xor(p, 8, 64);
        if (s < S) { vmax = fmaxf(vmax, p); vsum += p; }
      }
      vmax = fmaxf(vmax, __shfl_xor(vmax, 16, 64));
      vmax = fmaxf(vmax, __shfl_xor(vmax, 32, 64));
      vsum += __shfl_xor(vsum, 16, 64);
      vsum += __shfl_xor(vsum, 32, 64);
      if (lane == 0) M[(b * H_ + h) * L_ + l] = vmax - vsum * (1.0f / (float)LK_);
    } else {
      // ---- fill role: block grp fills out1v[grp*4096 .. +4096) ----
      const float iv = 1.0f / (float)LK_;
      const floatv4 fv = {iv, iv, iv, iv};
      int base = grp * 4096 + threadIdx.x;
#pragma unroll
      for (int j = 0; j < 16; ++j)
        __builtin_nontemporal_store(fv, &out1v[base + j * 256]);
    }
  } else {
    // ---- kVm role ----
    int blk = bx - 12288;
    int bh = blk >> 3, c = blk & 7;
    int b = bh >> 3, h = bh & 7;
    int t = threadIdx.x, lane = t & 63, w = t >> 6;
    int l0 = c * 256 + w * 64;
    float acc = 0.0f;
#pragma unroll 4
    for (int i = 0; i < 64; ++i)
      acc += V[(((b * L_ + l0 + i) * H_ + h) << 6) + lane];
    __shared__ float cred[4][64];
    cred[w][lane] = acc;
    __syncthreads();
    if (w == 0)
      partialV[(bh * 8 + c) * 64 + lane] =
          cred[0][lane] + cred[1][lane] + cred[2][lane] + cred[3][lane];
  }
}

// ---------------------------------------------------------------------------
// kB2: per (b,h): stable top-40 of M row, ONE WAVE, registers + static
// indexing only. Tie-break: lowest index. Also finishes V-mean.
// ---------------------------------------------------------------------------
__global__ __launch_bounds__(64) void kB2_topk(
    const float* __restrict__ M, const float* __restrict__ partialV,
    int* __restrict__ Mtop, float* __restrict__ meanV) {
  int bh = blockIdx.x;
  int lane = threadIdx.x;
  float v[32];
  int base = bh * L_;
#pragma unroll
  for (int i = 0; i < 32; ++i) v[i] = M[base + lane + i * 64];
  for (int it = 0; it < U_; ++it) {
    float best = -3.0e38f;
    int bi = 0x7fffffff;
#pragma unroll
    for (int i = 0; i < 32; ++i) {
      if (v[i] > best) { best = v[i]; bi = lane + i * 64; }
    }
#pragma unroll
    for (int off = 32; off > 0; off >>= 1) {
      float ov = __shfl_xor(best, off, 64);
      int oi = __shfl_xor(bi, off, 64);
      if (ov > best || (ov == best && oi < bi)) { best = ov; bi = oi; }
    }
    if (lane == 0) Mtop[bh * U_ + it] = bi;
    if ((bi & 63) == lane) {
#pragma unroll
      for (int i = 0; i < 32; ++i)
        if ((bi >> 6) == i) v[i] = -3.0e38f;
    }
  }
  float s = 0.0f;
#pragma unroll
  for (int c = 0; c < 8; ++c) s += partialV[(bh * 8 + c) * 64 + lane];
  meanV[(bh << 6) + lane] = s * (1.0f / (float)L_);
}

// ---------------------------------------------------------------------------
// kD: scores for the 40 selected queries, in place into attns rows (x 1/8),
// PLUS the out0 mean-broadcast fill (8 MB; meanV is ready post-kB2).
// Grid = (b,h) x 32 key-chunks of 64. 65-pad keeps LDS conflict-free.
// ---------------------------------------------------------------------------
__global__ __launch_bounds__(256) void kD_scores(
    const float* __restrict__ Q, const float* __restrict__ K,
    const int* __restrict__ Mtop, float* __restrict__ out1,
    floatv4* __restrict__ out0v, const float* __restrict__ meanV) {
  int bh = blockIdx.x >> 5;
  int kc = blockIdx.x & 31;
  int b = bh >> 3, h = bh & 7;
  __shared__ float Kt[64][65];
  __shared__ float Qt[U_][65];
  __shared__ int rows[U_];
  int t = threadIdx.x;
  int k0 = kc << 6;
  for (int i = t; i < 64 * 64; i += 256) {
    int r = i >> 6, e = i & 63;
    Kt[r][e] = K[(((b * L_ + k0 + r) * H_ + h) << 6) + e];
  }
  if (t < U_) rows[t] = Mtop[bh * U_ + t];
  __syncthreads();
  for (int i = t; i < U_ * 64; i += 256) {
    int u = i >> 6, e = i & 63;
    Qt[u][e] = Q[(((b * L_ + rows[u]) * H_ + h) << 6) + e];
  }
  __syncthreads();
  for (int p = t; p < U_ * 64; p += 256) {
    int u = p >> 6, k = p & 63;
    float s = 0.0f;
#pragma unroll
    for (int e = 0; e < 64; ++e) s += Qt[u][e] * Kt[k][e];
    out1[(size_t)(bh * LK_ + rows[u]) * LK_ + (k0 + k)] = s * 0.125f;
  }
  // ---- out0 fill: 524288 float4 over 512x256 threads = 4 per thread ----
  const int N0 = (B_ * L_ * H_ * E_) / 4;
  int gtid = blockIdx.x * 256 + t;
#pragma unroll
  for (int j = 0; j < 4; ++j) {
    int i = gtid + j * 512 * 256;
    if (i < N0) {
      int e4 = i & 15;
      int hh = (i >> 4) & 7;
      int bb = i >> 18;
      const floatv4* mp = (const floatv4*)(meanV + (((bb << 3) + hh) << 6));
      __builtin_nontemporal_store(mp[e4], &out0v[i]);
    }
  }
}

// ---------------------------------------------------------------------------
// kE: per selected row (640 wgs): in-place softmax, then ctx = p.V with
// float4 lanes (16 lanes/row, 4 rows in flight per wave).
// ---------------------------------------------------------------------------
__global__ __launch_bounds__(256) void kE_softmax_ctx(
    const float* __restrict__ V, const int* __restrict__ Mtop,
    float* __restrict__ out0, float* __restrict__ out1) {
  int gblk = blockIdx.x;
  int u = gblk % U_;
  int bh = gblk / U_;
  int b = bh >> 3, h = bh & 7;
  int t = threadIdx.x, lane = t & 63, w = t >> 6;
  int lu = Mtop[bh * U_ + u];
  float* row = out1 + (size_t)(bh * LK_ + lu) * LK_;
  float4* row4 = (float4*)row;
  float4 v0 = row4[t], v1 = row4[t + 256];
  float lmax = fmaxf(fmaxf(fmaxf(v0.x, v0.y), fmaxf(v0.z, v0.w)),
                     fmaxf(fmaxf(v1.x, v1.y), fmaxf(v1.z, v1.w)));
#pragma unroll
  for (int off = 32; off > 0; off >>= 1) lmax = fmaxf(lmax, __shfl_xor(lmax, off, 64));
  __shared__ float sred[4];
  if (lane == 0) sred[w] = lmax;
  __syncthreads();
  float gmax = fmaxf(fmaxf(sred[0], sred[1]), fmaxf(sred[2], sred[3]));
  __syncthreads();
  v0.x = __expf(v0.x - gmax); v0.y = __expf(v0.y - gmax);
  v0.z = __expf(v0.z - gmax); v0.w = __expf(v0.w - gmax);
  v1.x = __expf(v1.x - gmax); v1.y = __expf(v1.y - gmax);
  v1.z = __expf(v1.z - gmax); v1.w = __expf(v1.w - gmax);
  float lsum = v0.x + v0.y + v0.z + v0.w + v1.x + v1.y + v1.z + v1.w;
#pragma unroll
  for (int off = 32; off > 0; off >>= 1) lsum += __shfl_xor(lsum, off, 64);
  if (lane == 0) sred[w] = lsum;
  __syncthreads();
  float gsum = sred[0] + sred[1] + sred[2] + sred[3];
  float inv = 1.0f / gsum;
  v0.x *= inv; v0.y *= inv; v0.z *= inv; v0.w *= inv;
  v1.x *= inv; v1.y *= inv; v1.z *= inv; v1.w *= inv;
  __shared__ __attribute__((aligned(16))) float ps[2048];
  float4* ps4 = (float4*)ps;
  ps4[t] = v0; ps4[t + 256] = v1;
  row4[t] = v0; row4[t + 256] = v1;
  __syncthreads();
  // PV: wave w handles k in [w*512, w*512+512); 16 lanes per row, 4 rows/iter
  int g = lane >> 4, e4 = lane & 15;
  const float4* V4 = (const float4*)V;
  float4 acc = make_float4(0.f, 0.f, 0.f, 0.f);
  int kbase = w << 9;
#pragma unroll 4
  for (int kk = 0; kk < 512; kk += 4) {
    int k = kbase + kk + g;
    float pk = ps[k];
    int vrow = ((b * L_ + k) * H_ + h) << 4;
    float4 vv = V4[vrow + e4];
    acc.x += pk * vv.x; acc.y += pk * vv.y;
    acc.z += pk * vv.z; acc.w += pk * vv.w;
  }
#pragma unroll
  for (int off = 16; off <= 32; off <<= 1) {
    acc.x += __shfl_xor(acc.x, off, 64);
    acc.y += __shfl_xor(acc.y, off, 64);
    acc.z += __shfl_xor(acc.z, off, 64);
    acc.w += __shfl_xor(acc.w, off, 64);
  }
  __shared__ __attribute__((aligned(16))) float credf[4][64];
  if (lane < 16) *(float4*)&credf[w][e4 * 4] = acc;
  __syncthreads();
  if (w == 0) {
    float c = credf[0][lane] + credf[1][lane] + credf[2][lane] + credf[3][lane];
    out0[(((b * L_ + lu) * H_ + h) << 6) + lane] = c;
  }
}

// ---------------------------------------------------------------------------
extern "C" void kernel_launch(void* const* d_in, const int* in_sizes, int n_in,
                              void* d_out, int out_size, void* d_ws, size_t ws_size,
                              hipStream_t stream) {
  const float* Q = (const float*)d_in[0];
  const float* K = (const float*)d_in[1];
  const float* V = (const float*)d_in[2];
  const int* idxs = (const int*)d_in[3];
  int S = in_sizes[3] / L_;  // sample_k = 40

  float* out0 = (float*)d_out;
  float* out1 = out0 + (size_t)B_ * L_ * H_ * E_;

  // ws layout (floats): M[32768] | Mtop[640 i] | meanV[1024] | partialV[8192]
  float* M = (float*)d_ws;
  int* Mtop = (int*)((char*)d_ws + (size_t)32768 * 4);
  float* meanV = (float*)((char*)d_ws + (size_t)(32768 + 640) * 4);
  float* partialV = (float*)((char*)d_ws + (size_t)(32768 + 640 + 1024) * 4);

  kAF<<<dim3(12288 + B_ * H_ * 8), dim3(256), 0, stream>>>(
      Q, K, V, idxs, M, partialV, (floatv4*)out1, S);
  kB2_topk<<<dim3(B_ * H_), dim3(64), 0, stream>>>(M, partialV, Mtop, meanV);
  kD_scores<<<dim3(B_ * H_ * 32), dim3(256), 0, stream>>>(
      Q, K, Mtop, out1, (floatv4*)out0, meanV);
  kE_softmax_ctx<<<dim3(B_ * H_ * U_), dim3(256), 0, stream>>>(V, Mtop, out0, out1);
}